// Round 1
// baseline (249.478 us; speedup 1.0000x reference)
//
#include <hip/hip_runtime.h>
#include <hip/hip_bf16.h>

// Problem constants (from reference)
#define NN 64
#define CC 3
#define LL 4096
#define KK 128
#define SS 64
#define WW 4033           // LL - SS + 1
#define TILES 32          // ceil(WW / 128)

// ---------------------------------------------------------------------------
// Kernel 1: init d2min to +inf bits
__global__ void me_init(unsigned* __restrict__ d2g) {
    int i = blockIdx.x * blockDim.x + threadIdx.x;
    if (i < NN * KK) d2g[i] = 0x7F800000u;   // +inf
}

// ---------------------------------------------------------------------------
// Kernel 2: s2[c][k] = sum_s shp[c][k][s]^2   (384 values, one-off tiny)
__global__ void me_s2(const float* __restrict__ shp_g, float* __restrict__ s2g) {
    int t = blockIdx.x * blockDim.x + threadIdx.x;
    if (t < CC * KK) {
        const float* r = shp_g + t * SS;
        float a = 0.f;
        #pragma unroll 8
        for (int s = 0; s < SS; ++s) a += r[s] * r[s];
        s2g[t] = a;
    }
}

// ---------------------------------------------------------------------------
// Kernel 3: main. One block per (n, 128-window tile).
// Thread map: klocal = t&31 (shapelet lane), wc = t>>5 (window chunk of 16).
// Each thread: 16 windows x 4 shapelets (2 passes of 2), s-blocked by 8.
__global__ __launch_bounds__(256, 4) void me_main(
        const float* __restrict__ x,
        const float* __restrict__ shp_g,
        const float* __restrict__ s2g,
        unsigned* __restrict__ d2g) {
    const int b    = blockIdx.x;
    const int n    = b >> 5;          // 32 tiles per n
    const int tile = b & 31;
    const int w0   = tile * 128;
    const int t    = threadIdx.x;
    const int klocal = t & 31;
    const int wc     = t >> 5;

    __shared__ float xs[192];            // x tile: 128 + 64 - 1 = 191 -> 192
    __shared__ float x2s[128];           // sliding ||x_w||^2
    __shared__ float shp[KK * 68];       // shapelet tile, row stride 68 (pad)
    __shared__ unsigned red[KK];         // per-block min(d2) per k

    if (t < KK) red[t] = 0x7F800000u;

    const float* xb = x + (size_t)n * (CC * LL);

    for (int c = 0; c < CC; ++c) {
        __syncthreads();   // protect xs/shp reuse from previous channel

        // ---- stage x tile (192 floats = 48 float4) ----
        if (t < 48) {
            int i = t * 4;
            float4 v;
            if (w0 + i + 3 < LL) {
                v = *(const float4*)(xb + c * LL + w0 + i);
            } else {
                v.x = (w0 + i     < LL) ? xb[c * LL + w0 + i]     : 0.f;
                v.y = (w0 + i + 1 < LL) ? xb[c * LL + w0 + i + 1] : 0.f;
                v.z = (w0 + i + 2 < LL) ? xb[c * LL + w0 + i + 2] : 0.f;
                v.w = 0.f;
            }
            *(float4*)(xs + i) = v;
        }
        // ---- stage shapelet tile: 128 rows x 64 floats, LDS stride 68 ----
        {
            const float4* sg = (const float4*)(shp_g + c * (KK * SS));
            #pragma unroll
            for (int it = 0; it < 8; ++it) {
                int idx = t + it * 256;      // float4 index in [0, 2048)
                int k   = idx >> 4;          // 16 float4 per row
                int sq  = idx & 15;
                float4 v = sg[idx];
                *(float4*)(shp + k * 68 + sq * 4) = v;
            }
        }
        __syncthreads();

        // ---- sliding ||x_w||^2 for the 128 windows of this tile ----
        if (t < 128) {
            float a = 0.f;
            #pragma unroll 8
            for (int s = 0; s < SS; ++s) { float v = xs[t + s]; a += v * v; }
            x2s[t] = a;
        }
        __syncthreads();

        // ---- main: 2 passes x 2 shapelets x 16 windows per thread ----
        for (int p = 0; p < 2; ++p) {
            const int ka = klocal + 32 * (2 * p);
            const int kb = klocal + 32 * (2 * p + 1);
            float acc0[16], acc1[16];
            #pragma unroll
            for (int j = 0; j < 16; ++j) { acc0[j] = 0.f; acc1[j] = 0.f; }

            const float* xrow = xs + wc * 16;
            const float* sa = shp + ka * 68;
            const float* sb = shp + kb * 68;

            for (int s0 = 0; s0 < SS; s0 += 8) {
                float xseg[24];
                #pragma unroll
                for (int q = 0; q < 6; ++q)
                    *(float4*)(xseg + 4 * q) = *(const float4*)(xrow + s0 + 4 * q);
                float fa[8], fb[8];
                #pragma unroll
                for (int q = 0; q < 2; ++q) {
                    *(float4*)(fa + 4 * q) = *(const float4*)(sa + s0 + 4 * q);
                    *(float4*)(fb + 4 * q) = *(const float4*)(sb + s0 + 4 * q);
                }
                #pragma unroll
                for (int sj = 0; sj < 8; ++sj) {
                    #pragma unroll
                    for (int j = 0; j < 16; ++j) {
                        acc0[j] += xseg[sj + j] * fa[sj];
                        acc1[j] += xseg[sj + j] * fb[sj];
                    }
                }
            }

            // epilogue: d2 = x2[w] + s2[k] - 2*dot ; min over this thread's w
            float m0 = 3.4e38f, m1 = 3.4e38f;
            #pragma unroll
            for (int j = 0; j < 16; ++j) {
                int w = w0 + wc * 16 + j;
                if (w < WW) {
                    float xv = x2s[wc * 16 + j];
                    float v0 = xv - 2.f * acc0[j];
                    float v1 = xv - 2.f * acc1[j];
                    m0 = fminf(m0, v0);
                    m1 = fminf(m1, v1);
                }
            }
            m0 = fmaxf(m0 + s2g[c * KK + ka], 0.f);
            m1 = fmaxf(m1 + s2g[c * KK + kb], 0.f);
            // nonneg floats: IEEE bit pattern is monotone -> uint atomicMin
            atomicMin(&red[ka], __float_as_uint(m0));
            atomicMin(&red[kb], __float_as_uint(m1));
        }
    }
    __syncthreads();
    if (t < KK) atomicMin(&d2g[n * KK + t], red[t]);
}

// ---------------------------------------------------------------------------
// Kernel 4: finalize out = sqrt(d2min)
__global__ void me_fin(const unsigned* __restrict__ d2g, float* __restrict__ out) {
    int i = blockIdx.x * blockDim.x + threadIdx.x;
    if (i < NN * KK) out[i] = sqrtf(__uint_as_float(d2g[i]));
}

// ---------------------------------------------------------------------------
extern "C" void kernel_launch(void* const* d_in, const int* in_sizes, int n_in,
                              void* d_out, int out_size, void* d_ws, size_t ws_size,
                              hipStream_t stream) {
    const float* x   = (const float*)d_in[0];   // (N, C, L) fp32
    const float* shp = (const float*)d_in[1];   // (C, K, S) fp32
    unsigned* d2g = (unsigned*)d_ws;            // 8192 u32
    float*    s2g = (float*)d_ws + NN * KK;     // 384 f32
    float*    out = (float*)d_out;              // (N, 1, K) fp32

    hipLaunchKernelGGL(me_init, dim3((NN * KK + 255) / 256), dim3(256), 0, stream, d2g);
    hipLaunchKernelGGL(me_s2,   dim3(2), dim3(256), 0, stream, shp, s2g);
    hipLaunchKernelGGL(me_main, dim3(NN * TILES), dim3(256), 0, stream, x, shp, s2g, d2g);
    hipLaunchKernelGGL(me_fin,  dim3((NN * KK + 255) / 256), dim3(256), 0, stream, d2g, out);
}

// Round 2
// 103.532 us; speedup vs baseline: 2.4097x; 2.4097x over previous
//
#include <hip/hip_runtime.h>
#include <hip/hip_bf16.h>

#define NN 64
#define CC 3
#define LL 4096
#define KK 128
#define SS 64
#define WW 4033           // LL - SS + 1
#define TILES 32          // 32 tiles of 128 windows per n

typedef __attribute__((ext_vector_type(8))) short v8s;   // 8 bf16 (4 VGPR) MFMA A/B frag
typedef __attribute__((ext_vector_type(4))) float v4f;   // 4 fp32 MFMA C/D frag

// ---- ws layout (bytes) ----
// d2g:  u32[NN*KK]            @ 0        (32768 B)
// hs2g: f32[CC*KK]            @ 32768    (1536 B)
// shb:  ushort[CC*1024*8]     @ 34304    (49152 B)  fragment-order bf16 shapelets
#define WS_HS2_OFF 32768
#define WS_SHB_OFF 34304

__device__ __forceinline__ unsigned bf16_rne(float f) {
    unsigned u = __float_as_uint(f);
    return (u + 0x7FFFu + ((u >> 16) & 1u)) >> 16;
}

// ---------------------------------------------------------------------------
__global__ void me_init(unsigned* __restrict__ d2g) {
    int i = blockIdx.x * blockDim.x + threadIdx.x;
    if (i < NN * KK) d2g[i] = 0x7F800000u;   // +inf
}

// hs2g[c*K+k] = -0.5 * sum_s shp[c][k][s]^2
__global__ void me_hs2(const float* __restrict__ shp, float* __restrict__ hs2g) {
    int t = blockIdx.x * blockDim.x + threadIdx.x;
    if (t < CC * KK) {
        const float* r = shp + t * SS;
        float a = 0.f;
        #pragma unroll 8
        for (int s = 0; s < SS; ++s) a += r[s] * r[s];
        hs2g[t] = -0.5f * a;
    }
}

// Pack shapelets bf16 in MFMA A-fragment order.
// chunk index = ((c*8 + mtile)*2 + sc)*64 + lane ; chunk = 8 bf16 = 16 B:
//   shp[c][mtile*16 + (lane&15)][sc*32 + (lane>>4)*8 + j], j=0..7
__global__ void me_pack(const float* __restrict__ shp, uint4* __restrict__ shb) {
    int tid = blockIdx.x * blockDim.x + threadIdx.x;
    if (tid >= CC * 1024) return;
    int c  = tid >> 10;
    int r  = tid & 1023;
    int mt = r >> 7;
    int sc = (r >> 6) & 1;
    int l  = r & 63;
    int row  = mt * 16 + (l & 15);
    int koff = sc * 32 + (l >> 4) * 8;
    const float* s = shp + ((size_t)(c * KK + row)) * SS + koff;
    float4 f0 = *(const float4*)s;
    float4 f1 = *(const float4*)(s + 4);
    uint4 o;
    o.x = (bf16_rne(f0.y) << 16) | bf16_rne(f0.x);
    o.y = (bf16_rne(f0.w) << 16) | bf16_rne(f0.z);
    o.z = (bf16_rne(f1.y) << 16) | bf16_rne(f1.x);
    o.w = (bf16_rne(f1.w) << 16) | bf16_rne(f1.z);
    shb[tid] = o;
}

// ---------------------------------------------------------------------------
// Main: one block per (n, 128-window tile); 4 waves; wave handles 32 windows
// (2 n-tiles of 16) x all 128 shapelets (8 m-tiles) x K=64 (2 chunks of 32).
// acc init = -0.5*x2[w]; D = dot + init; epi adds -0.5*s2[k]; min d2 = -2*maxD.
__global__ __launch_bounds__(256, 2) void me_main(
        const float* __restrict__ x,
        const ushort* __restrict__ shb_g,
        const float* __restrict__ hs2g,
        unsigned* __restrict__ d2g) {

    __shared__ __align__(16) ushort shb[8192];   // 16 KB: frag-order A tile (1 channel)
    __shared__ __align__(16) float xs[192];      // x tile fp32
    __shared__ float ps[192];                    // prefix of squares
    __shared__ float ps2[4];                     // per-wave segment totals
    __shared__ float hx2s[128];                  // -0.5*x2 (or -1e30 invalid)
    __shared__ __align__(16) float hs2s[128];    // -0.5*s2 for current channel
    __shared__ unsigned red[128];

    const int b    = blockIdx.x;
    const int n    = b >> 5;
    const int tile = b & 31;
    const int w0   = tile * 128;
    const int t    = threadIdx.x;
    const int lane = t & 63, wave = t >> 6;
    const int quad = lane >> 4, col = lane & 15;
    const int wbase = wave * 32;                 // in-tile window base for this wave

    if (t < 128) red[t] = 0x7F800000u;

    float rmax[8][4];
    #pragma unroll
    for (int m = 0; m < 8; ++m)
        #pragma unroll
        for (int r = 0; r < 4; ++r) rmax[m][r] = -3.4e38f;

    const float* xb = x + (size_t)n * (CC * LL);

    for (int c = 0; c < CC; ++c) {
        __syncthreads();   // previous channel's readers done before restaging

        // ---- stage A tile: 1024 x 16B chunks, global -> LDS DMA ----
        {
            typedef __attribute__((address_space(1))) const uint4 gu4;
            typedef __attribute__((address_space(3))) uint4 lu4;
            const uint4* gbase = (const uint4*)(shb_g) + c * 1024;
            #pragma unroll
            for (int it = 0; it < 4; ++it) {
                const uint4* gp = gbase + (it * 256 + t);          // per-lane
                uint4* lp = (uint4*)shb + (it * 256 + wave * 64);  // wave-uniform
                __builtin_amdgcn_global_load_lds((gu4*)gp, (lu4*)lp, 16, 0, 0);
            }
        }
        // ---- stage x tile (192 fp32), zero-fill past L ----
        if (t < 48) {
            int i = t * 4, gi = w0 + i;
            float4 v;
            if (gi + 3 < LL) v = *(const float4*)(xb + c * LL + gi);
            else {
                v.x = (gi     < LL) ? xb[c * LL + gi]     : 0.f;
                v.y = (gi + 1 < LL) ? xb[c * LL + gi + 1] : 0.f;
                v.z = (gi + 2 < LL) ? xb[c * LL + gi + 2] : 0.f;
                v.w = 0.f;
            }
            *(float4*)(xs + i) = v;
        }
        // ---- stage -0.5*s2 for this channel ----
        if (t < 32)
            *(float4*)(hs2s + t * 4) = *(const float4*)(hs2g + c * KK + t * 4);
        __syncthreads();

        // ---- sliding -0.5*||x_w||^2 via prefix scan of squares ----
        if (wave < 3) {
            int i = wave * 64 + lane;
            float v = xs[i]; v = v * v;
            #pragma unroll
            for (int d = 1; d < 64; d <<= 1) {
                float u = __shfl_up(v, d, 64);
                if (lane >= d) v += u;
            }
            ps[i] = v;
            if (lane == 63) ps2[wave] = v;
        }
        __syncthreads();
        if (t < 128) {
            float s0 = ps2[0], s1 = ps2[1];
            int i1 = t + 63, sg1 = i1 >> 6;
            float b1 = (sg1 == 0) ? 0.f : ((sg1 == 1) ? s0 : (s0 + s1));
            float I1 = ps[i1] + b1;
            float I0 = 0.f;
            if (t > 0) {
                int i0 = t - 1, sg0 = i0 >> 6;
                float b0 = (sg0 == 0) ? 0.f : ((sg0 == 1) ? s0 : (s0 + s1));
                I0 = ps[i0] + b0;
            }
            float x2 = I1 - I0;
            hx2s[t] = (w0 + t < WW) ? (-0.5f * x2) : -1e30f;
        }
        __syncthreads();   // also drains global_load_lds before shb reads

        // ---- MFMA phase ----
        v4f acc[8][2];
        float hx0 = hx2s[wbase + col];
        float hx1 = hx2s[wbase + 16 + col];
        #pragma unroll
        for (int m = 0; m < 8; ++m) {
            v4f a0 = {hx0, hx0, hx0, hx0};
            v4f a1 = {hx1, hx1, hx1, hx1};
            acc[m][0] = a0; acc[m][1] = a1;
        }
        #pragma unroll
        for (int sc = 0; sc < 2; ++sc) {
            v8s bf[2];
            #pragma unroll
            for (int nt = 0; nt < 2; ++nt) {
                const float* xp = xs + (wbase + nt * 16 + col + sc * 32 + quad * 8);
                float f0 = xp[0], f1 = xp[1], f2 = xp[2], f3 = xp[3];
                float f4 = xp[4], f5 = xp[5], f6 = xp[6], f7 = xp[7];
                union { v8s v; unsigned u[4]; } bu;
                bu.u[0] = __builtin_amdgcn_perm(__float_as_uint(f1), __float_as_uint(f0), 0x07060302u);
                bu.u[1] = __builtin_amdgcn_perm(__float_as_uint(f3), __float_as_uint(f2), 0x07060302u);
                bu.u[2] = __builtin_amdgcn_perm(__float_as_uint(f5), __float_as_uint(f4), 0x07060302u);
                bu.u[3] = __builtin_amdgcn_perm(__float_as_uint(f7), __float_as_uint(f6), 0x07060302u);
                bf[nt] = bu.v;
            }
            #pragma unroll
            for (int m = 0; m < 8; ++m) {
                v8s af = *(const v8s*)(shb + ((m * 2 + sc) * 64 + lane) * 8);
                acc[m][0] = __builtin_amdgcn_mfma_f32_16x16x32_bf16(af, bf[0], acc[m][0], 0, 0, 0);
                acc[m][1] = __builtin_amdgcn_mfma_f32_16x16x32_bf16(af, bf[1], acc[m][1], 0, 0, 0);
            }
        }
        // ---- per-channel epilogue: add -0.5*s2, running max ----
        #pragma unroll
        for (int m = 0; m < 8; ++m) {
            v4f h = *(const v4f*)(hs2s + m * 16 + quad * 4);
            #pragma unroll
            for (int r = 0; r < 4; ++r)
                rmax[m][r] = fmaxf(rmax[m][r],
                                   fmaxf(acc[m][0][r], acc[m][1][r]) + h[r]);
        }
    }

    // ---- reduce over the 16 window-columns (same k set per quad) ----
    #pragma unroll
    for (int m = 0; m < 8; ++m) {
        #pragma unroll
        for (int r = 0; r < 4; ++r) {
            float v = rmax[m][r];
            v = fmaxf(v, __shfl_xor(v, 1, 64));
            v = fmaxf(v, __shfl_xor(v, 2, 64));
            v = fmaxf(v, __shfl_xor(v, 4, 64));
            v = fmaxf(v, __shfl_xor(v, 8, 64));
            rmax[m][r] = v;
        }
    }
    if (col == 0) {   // 4 lanes per wave (one per quad)
        #pragma unroll
        for (int m = 0; m < 8; ++m)
            #pragma unroll
            for (int r = 0; r < 4; ++r) {
                int k = m * 16 + quad * 4 + r;
                float d2 = fmaxf(-2.f * rmax[m][r], 0.f);
                atomicMin(&red[k], __float_as_uint(d2));
            }
    }
    __syncthreads();
    if (t < 128) atomicMin(&d2g[n * KK + t], red[t]);
}

// ---------------------------------------------------------------------------
__global__ void me_fin(const unsigned* __restrict__ d2g, float* __restrict__ out) {
    int i = blockIdx.x * blockDim.x + threadIdx.x;
    if (i < NN * KK) out[i] = sqrtf(__uint_as_float(d2g[i]));
}

// ---------------------------------------------------------------------------
extern "C" void kernel_launch(void* const* d_in, const int* in_sizes, int n_in,
                              void* d_out, int out_size, void* d_ws, size_t ws_size,
                              hipStream_t stream) {
    const float* x   = (const float*)d_in[0];   // (N, C, L) fp32
    const float* shp = (const float*)d_in[1];   // (C, K, S) fp32
    unsigned* d2g  = (unsigned*)d_ws;
    float*    hs2g = (float*)((char*)d_ws + WS_HS2_OFF);
    uint4*    shb  = (uint4*)((char*)d_ws + WS_SHB_OFF);
    const ushort* shb_u = (const ushort*)shb;
    float* out = (float*)d_out;

    hipLaunchKernelGGL(me_init, dim3((NN * KK + 255) / 256), dim3(256), 0, stream, d2g);
    hipLaunchKernelGGL(me_hs2,  dim3(2), dim3(256), 0, stream, shp, hs2g);
    hipLaunchKernelGGL(me_pack, dim3((CC * 1024 + 255) / 256), dim3(256), 0, stream, shp, shb);
    hipLaunchKernelGGL(me_main, dim3(NN * TILES), dim3(256), 0, stream, x, shb_u, hs2g, d2g);
    hipLaunchKernelGGL(me_fin,  dim3((NN * KK + 255) / 256), dim3(256), 0, stream, d2g, out);
}